// Round 1
// 521.704 us; speedup vs baseline: 1.0910x; 1.0910x over previous
//
#include <hip/hip_runtime.h>
#include <hip/hip_bf16.h>

typedef unsigned short u16;
typedef __attribute__((ext_vector_type(8))) __bf16 bf16x8;
typedef __attribute__((ext_vector_type(4))) float f32x4;

#define DIN 4096
#define DOUT 4096
#define MROWS 8192

__device__ __forceinline__ u16 f2bf(float f) {
  unsigned int u = __float_as_uint(f);
  u += 0x7fffu + ((u >> 16) & 1u);   // RNE; inputs are finite randoms
  return (u16)(u >> 16);
}

__device__ __forceinline__ void gl2lds16(const void* g, void* l) {
  __builtin_amdgcn_global_load_lds(
      (const __attribute__((address_space(1))) unsigned int*)g,
      (__attribute__((address_space(3))) unsigned int*)l, 16, 0, 0);
}

// ---------------------------------------------------------------------------
// Kernel 0: x fp32 -> bf16 (streaming; was fused into coeffgemm)
__global__ __launch_bounds__(256) void convx(const float* __restrict__ x,
                                             u16* __restrict__ Xb) {
  size_t i = ((size_t)blockIdx.x * 256 + threadIdx.x) * 4;
  float4 v = *(const float4*)(x + i);
  ushort4 o;
  o.x = f2bf(v.x); o.y = f2bf(v.y); o.z = f2bf(v.z); o.w = f2bf(v.w);
  *(ushort4*)(Xb + i) = o;
}

// ---------------------------------------------------------------------------
// Kernel 1: W fp32 -> bf16 (B^T layout is W's native [DOUT][DIN] layout)
__global__ __launch_bounds__(256) void convw(const float* __restrict__ W,
                                             u16* __restrict__ Wb) {
  size_t i = ((size_t)blockIdx.x * 256 + threadIdx.x) * 4;
  float4 v = *(const float4*)(W + i);
  ushort4 o;
  o.x = f2bf(v.x); o.y = f2bf(v.y); o.z = f2bf(v.z); o.w = f2bf(v.w);
  *(ushort4*)(Wb + i) = o;
}

// ---------------------------------------------------------------------------
// Kernel 2: Ub[n][c] = bf16(lora_up_flat[c][n]), c<32 (experts 0..3), transpose
__global__ __launch_bounds__(256) void convu(const float* __restrict__ up,
                                             u16* __restrict__ Ub) {
  int n = blockIdx.x * 256 + threadIdx.x;
  union { u16 us[32]; uint4 q[4]; } o;
  #pragma unroll
  for (int c = 0; c < 32; ++c) o.us[c] = f2bf(up[(size_t)c * DOUT + n]);
  uint4* dst = (uint4*)(Ub + (size_t)n * 32);
  #pragma unroll
  for (int q = 0; q < 4; ++q) dst[q] = o.q[q];
}

// ---------------------------------------------------------------------------
// Kernel 3a: pack coeff-GEMM weights Wt[48][4096] bf16.
__global__ __launch_bounds__(256) void wtprep(const float* __restrict__ route,
                                              const float* __restrict__ down,
                                              u16* __restrict__ Wt) {
  const int c = blockIdx.y;
  const int k0 = blockIdx.x * 1024 + threadIdx.x * 4;
  const float* route3 = route + 3 * DIN * 5;  // lora_route[3]
  float v[4];
  #pragma unroll
  for (int j = 0; j < 4; ++j) {
    int k = k0 + j;
    float f;
    if (c < 3)       f = route3[(size_t)k * 5 + c];
    else if (c < 35) f = down[(size_t)((c - 3) >> 3) * DIN * 8 + (size_t)k * 8 + ((c - 3) & 7)];
    else             f = 0.f;
    v[j] = f;
  }
  ushort4 o;
  o.x = f2bf(v[0]); o.y = f2bf(v[1]); o.z = f2bf(v[2]); o.w = f2bf(v[3]);
  *(ushort4*)(Wt + (size_t)c * DIN + k0) = o;
}

// ---------------------------------------------------------------------------
// Kernel 3b: MFMA tall-skinny GEMM Pw[split][8192][48] = Xb . Wt^T over K-slice.
// Now reads pre-cast bf16 Xb via global_load_lds (same XOR swizzle as main GEMM).
__global__ __launch_bounds__(256) void coeffgemm(
    const u16* __restrict__ Xb, const u16* __restrict__ Wt,
    float* __restrict__ Pw) {
  __shared__ __align__(16) u16 As[128 * 64];
  __shared__ __align__(16) u16 Bs[48 * 64];
  const int tid = threadIdx.x;
  const int m0 = blockIdx.x * 128;
  const int kb = blockIdx.y * 512;
  const int lane = tid & 63;
  const int w = tid >> 6;
  const int wr = w * 32;
  const int fm = lane & 15;
  const int xr = fm & 7;
  const int qd = lane >> 4;

  f32x4 acc[2][3];
  #pragma unroll
  for (int i = 0; i < 2; ++i)
    #pragma unroll
    for (int j = 0; j < 3; ++j) acc[i][j] = (f32x4){0.f, 0.f, 0.f, 0.f};

  const int srow = tid >> 3;                        // 0..31
  const int scol = ((tid & 7) ^ (srow & 7)) * 8;    // swizzled source chunk
  const u16* gA = Xb + (size_t)(m0 + srow) * DIN + kb + scol;
  u16* lA = As + tid * 8;

  for (int kc = 0; kc < 512; kc += 64) {
    gl2lds16(Wt + (size_t)srow * DIN + kb + kc + scol, Bs + tid * 8);
    if (tid < 128) {
      int u = 256 + tid;
      int usw = ((u & 7) ^ ((u >> 3) & 7)) * 8;
      gl2lds16(Wt + (size_t)(u >> 3) * DIN + kb + kc + usw, Bs + u * 8);
    }
    #pragma unroll
    for (int it = 0; it < 4; ++it)
      gl2lds16(gA + kc + (size_t)(it * 32) * DIN, lA + it * 2048);
    __syncthreads();
    #pragma unroll
    for (int kk = 0; kk < 64; kk += 32) {
      const int q = (kk >> 3) + qd;
      bf16x8 af[2], bfr[3];
      #pragma unroll
      for (int i = 0; i < 2; ++i)
        af[i] = *(const bf16x8*)(As + (wr + i * 16 + fm) * 64 + ((q ^ xr) << 3));
      #pragma unroll
      for (int j = 0; j < 3; ++j)
        bfr[j] = *(const bf16x8*)(Bs + (j * 16 + fm) * 64 + ((q ^ xr) << 3));
      #pragma unroll
      for (int i = 0; i < 2; ++i)
        #pragma unroll
        for (int j = 0; j < 3; ++j)
          acc[i][j] = __builtin_amdgcn_mfma_f32_16x16x32_bf16(af[i], bfr[j], acc[i][j], 0, 0, 0);
    }
    __syncthreads();
  }
  const int em = (lane >> 4) * 4;
  const int en = lane & 15;
  const size_t pbase = (size_t)blockIdx.y * MROWS;
  #pragma unroll
  for (int i = 0; i < 2; ++i)
    #pragma unroll
    for (int j = 0; j < 3; ++j)
      #pragma unroll
      for (int r = 0; r < 4; ++r)
        Pw[(pbase + m0 + wr + i * 16 + em + r) * 48 + j * 16 + en] = acc[i][j][r];
}

// ---------------------------------------------------------------------------
// Kernel 3c: reduce 8 K-split partials, softmax gate, emit Cb[8192][32] bf16.
__global__ __launch_bounds__(256) void reduce_coeff(const float* __restrict__ Pw,
                                                    u16* __restrict__ Cb) {
  const int m = blockIdx.x * 256 + threadIdx.x;
  float s[48];
  #pragma unroll
  for (int c = 0; c < 48; ++c) s[c] = 0.f;
  for (int sp = 0; sp < 8; ++sp) {
    const float4* p = (const float4*)(Pw + ((size_t)sp * MROWS + m) * 48);
    #pragma unroll
    for (int q = 0; q < 12; ++q) {
      float4 v = p[q];
      s[q * 4 + 0] += v.x; s[q * 4 + 1] += v.y;
      s[q * 4 + 2] += v.z; s[q * 4 + 3] += v.w;
    }
  }
  float mx = fmaxf(s[0], fmaxf(s[1], s[2]));
  float e0 = __expf(s[0] - mx), e1 = __expf(s[1] - mx), e2 = __expf(s[2] - mx);
  float inv = 1.f / (e0 + e1 + e2);
  float om0 = e0 * inv, om1 = e1 * inv, om2 = e2 * inv;
  union { u16 us[32]; uint4 q[4]; } o;
  #pragma unroll
  for (int c = 0; c < 32; ++c) {
    float wgt = (c < 8) ? om0 : (c < 16) ? om1 : (c < 24) ? om2 : 1.f;
    o.us[c] = f2bf(s[3 + c] * wgt);
  }
  uint4* dst = (uint4*)(Cb + (size_t)m * 32);
  #pragma unroll
  for (int q = 0; q < 4; ++q) dst[q] = o.q[q];
}

// ---------------------------------------------------------------------------
// Kernel 4: out = Xb @ Wb^T + Cb @ Ub^T.
// 256x256 tile, BK=64, 512 threads (8 waves: 2M x 4N), 8-phase schedule:
// per K-tile 4 phases of {ds_read subtile | stage 1 half-tile | s_barrier |
// setprio(1) 16xMFMA setprio(0) | s_barrier}, ONE s_waitcnt vmcnt(4) per tile
// (2 half-tiles always in flight; never drained mid-loop).
// LDS: per operand 4 regions of 16KiB = [2 tile-parities][2 K-halves];
// region layout packs row pairs: chunk(lrow, c'), c' = ((row&1)*4 + k8) ^ (lrow&7)
// -> uniform 2-way bank access on ds_read_b128 (free).
// Liveness: region (b,h0) read at p1/p2, restaged at p3 (barrier-separated);
// (b,h1) read p3/p4, restaged at next tile's p1. vmcnt(4) at p4 guarantees the
// next tile's 4 half-tiles have landed while keeping the 2 newest in flight.
// K-summation order identical to previous kernel (tile-ascending, kk0 then kk32,
// LoRA K=32 tail last) -> bit-identical output.

#define MF(a, b, c) __builtin_amdgcn_mfma_f32_16x16x32_bf16(a, b, c, 0, 0, 0)

#define MROW(A, I) \
  acc[I][0] = MF(A, bfr0, acc[I][0]); \
  acc[I][1] = MF(A, bfr1, acc[I][1]); \
  acc[I][2] = MF(A, bfr2, acc[I][2]); \
  acc[I][3] = MF(A, bfr3, acc[I][3]);

#define VM4 asm volatile("s_waitcnt vmcnt(4)" ::: "memory")
#define VM0 asm volatile("s_waitcnt vmcnt(0)" ::: "memory")

#define STA(REG, KOFF) { const u16* s_ = gA + (KOFF); \
  gl2lds16(s_, dA + (REG) * 8192); \
  gl2lds16(s_ + 128 * 4096, dA + (REG) * 8192 + 4096); }
#define STB(REG, KOFF) { const u16* s_ = gB + (KOFF); \
  gl2lds16(s_, dB + (REG) * 8192); \
  gl2lds16(s_ + 128 * 4096, dB + (REG) * 8192 + 4096); }
#define STC { const u16* s_ = Cb + (size_t)(m0 + gr1) * 32 + kc1; \
  gl2lds16(s_, dA); gl2lds16(s_ + 128 * 32, dA + 4096); }
#define STU { const u16* s_ = Ub + (size_t)(n0 + gr1) * 32 + kc1; \
  gl2lds16(s_, dB); gl2lds16(s_ + 128 * 32, dB + 4096); }

#define PH(REG, IH, LOADB, ISSUE, VMX) { \
  const u16* ap_ = sm + (REG) * 8192 + wmoff + (IH) * 2048 + off0; \
  bf16x8 af0 = *(const bf16x8*)(ap_); \
  bf16x8 af1 = *(const bf16x8*)(ap_ + 512); \
  bf16x8 af2 = *(const bf16x8*)(ap_ + 1024); \
  bf16x8 af3 = *(const bf16x8*)(ap_ + 1536); \
  if (LOADB) { \
    const u16* bp_ = sm + 32768 + (REG) * 8192 + wnoff + off0; \
    bfr0 = *(const bf16x8*)(bp_); \
    bfr1 = *(const bf16x8*)(bp_ + 512); \
    bfr2 = *(const bf16x8*)(bp_ + 1024); \
    bfr3 = *(const bf16x8*)(bp_ + 1536); \
  } \
  ISSUE; \
  asm volatile("" ::: "memory"); \
  __builtin_amdgcn_s_barrier(); \
  __builtin_amdgcn_s_setprio(1); \
  MROW(af0, (IH) * 4 + 0) \
  MROW(af1, (IH) * 4 + 1) \
  MROW(af2, (IH) * 4 + 2) \
  MROW(af3, (IH) * 4 + 3) \
  __builtin_amdgcn_s_setprio(0); \
  VMX; \
  asm volatile("" ::: "memory"); \
  __builtin_amdgcn_s_barrier(); \
}

#define TILE(B, I1, I2, I3, I4, VMX) { \
  bf16x8 bfr0, bfr1, bfr2, bfr3; \
  PH((B) * 2 + 0, 0, 1, I1, (void)0) \
  PH((B) * 2 + 0, 1, 0, I2, (void)0) \
  PH((B) * 2 + 1, 0, 1, I3, (void)0) \
  PH((B) * 2 + 1, 1, 0, I4, VMX) \
}

__global__ __launch_bounds__(512, 2) void gemm_fused8(
    const u16* __restrict__ Xb, const u16* __restrict__ Wb,
    const u16* __restrict__ Cb, const u16* __restrict__ Ub,
    float* __restrict__ out) {
  __shared__ __align__(16) u16 sm[65536];   // 128 KiB: A [0,32768), B [32768,65536)
  const int tid = threadIdx.x;
  const int bid = blockIdx.x;
  const int wg = (bid & 7) * 64 + (bid >> 3);   // XCD swizzle (nwg=512, 8|512)
  const int mt = wg >> 4;                        // 32 M-tiles
  const int nt = wg & 15;                        // 16 N-tiles
  const int m0 = mt * 256;
  const int n0 = nt * 256;
  const int lane = tid & 63;
  const int w = tid >> 6;
  const int wm = w >> 2;        // 0..1  (128 rows each)
  const int wn = w & 3;         // 0..3  (64 cols each)
  const int fm = lane & 15;
  const int qd = lane >> 4;
  // fragment read offset (u16): lrow = fm>>1; chunk c' = ((fm&1)*4+qd) ^ lrow
  const int off0 = (fm >> 1) * 64 + (((((fm & 1) << 2) | qd)) ^ (fm >> 1)) * 8;
  const int wmoff = wm * 4096;
  const int wnoff = wn * 2048;

  // staging map: thread t stages LDS chunks t and t+512 of a 16KiB region.
  // chunk L: lrow=L>>3, c'=L&7, c=c'^(lrow&7) -> grow=2*lrow+(c>>2), k8=c&3
  const int c1 = (tid & 7) ^ ((tid >> 3) & 7);
  const int gr1 = 2 * (tid >> 3) + (c1 >> 2);
  const int kc1 = (c1 & 3) * 8;
  const u16* gA = Xb + (size_t)(m0 + gr1) * 4096 + kc1;
  const u16* gB = Wb + (size_t)(n0 + gr1) * 4096 + kc1;
  u16* dA = sm + tid * 8;
  u16* dB = sm + 32768 + tid * 8;

  f32x4 acc[8][4];
  #pragma unroll
  for (int i = 0; i < 8; ++i)
    #pragma unroll
    for (int j = 0; j < 4; ++j) acc[i][j] = (f32x4){0.f, 0.f, 0.f, 0.f};

  // prologue: tile0 (regs 0,1), tile1 h0 (reg 2). vmcnt(4) leaves tile1-h0 in flight.
  STA(0, 0)  STB(0, 0)
  STA(1, 32) STB(1, 32)
  STA(2, 64) STB(2, 64)
  VM4;
  asm volatile("" ::: "memory");
  __builtin_amdgcn_s_barrier();

  // main loop: tiles 0..61 (two per iteration). Issues per tile:
  // p1/p2 -> (T+1) K-half1; p3/p4 -> (T+2) K-half0.
  for (int T = 0; T < 62; T += 2) {
    TILE(0, STA(3, T * 64 + 96),  STB(3, T * 64 + 96),
            STA(0, T * 64 + 128), STB(0, T * 64 + 128), VM4)
    TILE(1, STA(1, T * 64 + 160), STB(1, T * 64 + 160),
            STA(2, T * 64 + 192), STB(2, T * 64 + 192), VM4)
  }
  // tile 62: issue tile63 h1; drain (tile63 must be fully landed).
  TILE(0, STA(3, 4064), STB(3, 4064), (void)0, (void)0, VM0)
  // tile 63: issue LoRA stages (Cb->A reg0, Ub->B reg0); drain.
  TILE(1, STC, STU, (void)0, (void)0, VM0)

  // LoRA K=32 tail from regions A0/B0 (same packed layout, 32-wide K)
  {
    const u16* ap = sm + wmoff + off0;
    const u16* bp = sm + 32768 + wnoff + off0;
    bf16x8 bfr0 = *(const bf16x8*)(bp);
    bf16x8 bfr1 = *(const bf16x8*)(bp + 512);
    bf16x8 bfr2 = *(const bf16x8*)(bp + 1024);
    bf16x8 bfr3 = *(const bf16x8*)(bp + 1536);
    #pragma unroll
    for (int i = 0; i < 8; ++i) {
      bf16x8 a = *(const bf16x8*)(ap + i * 512);
      acc[i][0] = MF(a, bfr0, acc[i][0]);
      acc[i][1] = MF(a, bfr1, acc[i][1]);
      acc[i][2] = MF(a, bfr2, acc[i][2]);
      acc[i][3] = MF(a, bfr3, acc[i][3]);
    }
  }

  // epilogue: C/D layout col=lane&15, row=(lane>>4)*4+reg
  const int em = qd * 4;
  const int en = fm;
  const size_t obase = (size_t)(m0 + wm * 128) * DOUT + n0 + wn * 64 + en;
  #pragma unroll
  for (int i = 0; i < 8; ++i)
    #pragma unroll
    for (int j = 0; j < 4; ++j)
      #pragma unroll
      for (int r = 0; r < 4; ++r)
        out[obase + (size_t)(i * 16 + em + r) * DOUT + j * 16] = acc[i][j][r];
}

// ---------------------------------------------------------------------------
extern "C" void kernel_launch(void* const* d_in, const int* in_sizes, int n_in,
                              void* d_out, int out_size, void* d_ws, size_t ws_size,
                              hipStream_t stream) {
  const float* x     = (const float*)d_in[0];  // [4,2048,4096]
  const float* W     = (const float*)d_in[1];  // [4096,4096]
  const float* down  = (const float*)d_in[2];  // [5,4096,8]
  const float* up    = (const float*)d_in[3];  // [5,8,4096]
  const float* route = (const float*)d_in[4];  // [5,4096,5]
  float* out = (float*)d_out;

  char* ws = (char*)d_ws;
  u16*   Xb = (u16*)ws;                        // 64 MiB
  u16*   Wb = (u16*)(ws + 67108864);           // 32 MiB
  u16*   Cb = (u16*)(ws + 100663296);          // 512 KiB
  u16*   Ub = (u16*)(ws + 101187584);          // 256 KiB
  u16*   Wt = (u16*)(ws + 101449728);          // 384 KiB
  float* Pw = (float*)(ws + 101842944);        // 12 MiB

  convx<<<32768, 256, 0, stream>>>(x, Xb);
  convw<<<16384, 256, 0, stream>>>(W, Wb);
  convu<<<16, 256, 0, stream>>>(up, Ub);
  wtprep<<<dim3(4, 48), 256, 0, stream>>>(route, down, Wt);
  coeffgemm<<<dim3(64, 8), 256, 0, stream>>>(Xb, Wt, Pw);
  reduce_coeff<<<32, 256, 0, stream>>>(Pw, Cb);
  gemm_fused8<<<512, 512, 0, stream>>>(Xb, Wb, Cb, Ub, out);
}